// Round 5
// baseline (765.894 us; speedup 1.0000x reference)
//
#include <hip/hip_runtime.h>
#include <hip/hip_fp16.h>

#define BS 64
#define LS 512
#define CL 32
#define WD 300
#define NC 100
#define CD 100
#define PD 100
#define NF 100
#define KK 3
#define OPAD 128                  // k-row padded to 128 f16 = 256 B = 8 full bank sweeps
#define PROW (KK*OPAD)            // 384 f16 = 768 B per char
#define PBYTES (NC*PROW*2)        // 76800 B
#define OUTD 501
#define TPB 64                    // tokens per block (both kernels)
#define NTHR 1024

typedef _Float16 h2 __attribute__((ext_vector_type(2)));

// ---------- Kernel 1: P[c][k][o] = sum_i conv_w[o,i,k] * char_table[c,i] (f16) ----------
__global__ void precompute_P(const float* __restrict__ conv_w,
                             const float* __restrict__ char_table,
                             _Float16* __restrict__ P) {
    const int c = blockIdx.x;      // 0..99
    const int k = blockIdx.y;      // 0..2
    const int o = threadIdx.x;     // 0..127
    __shared__ float row[CD];
    if (o < CD) row[o] = char_table[c * CD + o];
    __syncthreads();
    float acc = 0.f;
    if (o < NF) {
        const float* w = conv_w + o * (CD * KK) + k;
        #pragma unroll 4
        for (int i = 0; i < CD; ++i) acc += w[i * KK] * row[i];
    }
    P[(c * KK + k) * OPAD + o] = (_Float16)acc;    // o in [100,128) stores 0
}

// ---------- Kernel A: streaming copies (word + pos) + privacy distance ----------
__global__ __launch_bounds__(NTHR, 8) void copy_kernel(
        const int* __restrict__ input_word,
        const int* __restrict__ input_pos,
        const float* __restrict__ word_table,
        const float* __restrict__ pos_table,
        float* __restrict__ out) {
    __shared__ unsigned long long s_mask[LS / 64];      // 64 B
    const int tid  = threadIdx.x;
    const int tok0 = blockIdx.x * TPB;
    const int row  = tok0 >> 9;

    // privacy-mask ballot for this block's row
    if (tid < LS) {
        const int p = input_pos[row * LS + tid];
        const bool pm = (p == 3) | (p == 7) | (p == 11);
        const unsigned long long b = __ballot(pm);
        if ((tid & 63) == 0) s_mask[tid >> 6] = b;
    }

    // word: out[:, 1:301] — float4 gathers, scalar stores (L2 write-combines)
    for (int i = tid; i < TPB * (WD / 4); i += NTHR) {
        const int t = i / (WD / 4);
        const int j = i - t * (WD / 4);
        const int w = input_word[tok0 + t];
        const float4 v = ((const float4*)word_table)[(size_t)w * (WD / 4) + j];
        float* o = out + (size_t)(tok0 + t) * OUTD + 1 + 4 * j;
        o[0] = v.x; o[1] = v.y; o[2] = v.z; o[3] = v.w;
    }
    // pos: out[:, 401:501]
    for (int i = tid; i < TPB * (PD / 4); i += NTHR) {
        const int t = i / (PD / 4);
        const int j = i - t * (PD / 4);
        const int p = input_pos[tok0 + t];
        const float4 v = ((const float4*)pos_table)[p * (PD / 4) + j];
        float* o = out + (size_t)(tok0 + t) * OUTD + 401 + 4 * j;
        o[0] = v.x; o[1] = v.y; o[2] = v.z; o[3] = v.w;
    }

    __syncthreads();

    // privacy distance: out[:, 0]
    if (tid < TPB) {
        const int j = (tok0 & (LS - 1)) + tid;
        const int wj = j >> 6, bj = j & 63;
        int last = -1000;
        {
            unsigned long long x = s_mask[wj] & ((2ull << bj) - 1ull);
            int w = wj;
            while (true) {
                if (x) { last = w * 64 + 63 - __clzll(x); break; }
                if (--w < 0) break;
                x = s_mask[w];
            }
        }
        int nxt = 1000;
        {
            unsigned long long x = s_mask[wj] & (~0ull << bj);
            int w = wj;
            while (true) {
                if (x) { nxt = w * 64 + (int)__ffsll((long long)x) - 1; break; }
                if (++w >= LS / 64) break;
                x = s_mask[w];
            }
        }
        out[(size_t)(tok0 + tid) * OUTD] = (float)min(j - last, nxt - j);
    }
}

// ---------- Kernel B: char CNN, conflict-free LDS layout ----------
// 16 lanes per token; each lane owns 8 filters (16 B). Char bases are 768 B
// (bank-0 aligned) and each 16-lane group reads 256 B contiguous -> every
// ds_read_b128 covers all 32 banks exactly twice: zero bank conflicts.
__global__ __launch_bounds__(NTHR, 8) void char_kernel(
        const int* __restrict__ input_char,
        const float* __restrict__ conv_b,
        const _Float16* __restrict__ Pg,
        float* __restrict__ out) {
    __shared__ alignas(16) _Float16 Pl[NC * PROW];      // 76800 B
    __shared__ alignas(16) unsigned char s_char[TPB * CL]; // 2048 B packed char ids

    const int tid  = threadIdx.x;
    const int tok0 = blockIdx.x * TPB;

    // stage P (4800 x 16B)
    {
        const uint4* src = (const uint4*)Pg;
        uint4* dst = (uint4*)Pl;
        for (int i = tid; i < PBYTES / 16; i += NTHR) dst[i] = src[i];
    }
    // stage char ids as packed bytes (512 dwords)
    if (tid < (TPB * CL) / 4) {
        const int4 c4 = ((const int4*)(input_char + tok0 * CL))[tid];
        ((unsigned*)s_char)[tid] =
            (unsigned)c4.x | ((unsigned)c4.y << 8) | ((unsigned)c4.z << 16) | ((unsigned)c4.w << 24);
    }
    __syncthreads();

    const int tl = tid >> 4;        // token in block (0..63)
    const int l  = tid & 15;        // lane-in-token = filter quad (0..15)

    // preload my token's 32 char ids (packed) into 8 dwords
    const uint4 u0 = ((const uint4*)s_char)[tl * 2];
    const uint4 u1 = ((const uint4*)s_char)[tl * 2 + 1];
    const unsigned idw[8] = {u0.x, u0.y, u0.z, u0.w, u1.x, u1.y, u1.z, u1.w};

    const char* Pb = (const char*)Pl + l * 16;
    h2 a0[4], a1[4], m[4];
    #pragma unroll
    for (int i = 0; i < 4; ++i) {
        a0[i] = (h2)(_Float16)0;
        a1[i] = (h2)(_Float16)0;
        m[i]  = (h2)(_Float16)(-60000.f);
    }
    #pragma unroll
    for (int t = 0; t < CL; ++t) {
        const unsigned id = (idw[t >> 2] >> (8 * (t & 3))) & 0xFFu;
        const int ca = (int)(id * (PROW * 2));          // id * 768
        const uint4 r0 = *(const uint4*)(Pb + ca + 0 * (OPAD * 2));
        const uint4 r1 = *(const uint4*)(Pb + ca + 1 * (OPAD * 2));
        const uint4 r2 = *(const uint4*)(Pb + ca + 2 * (OPAD * 2));
        const unsigned rr0[4] = {r0.x, r0.y, r0.z, r0.w};
        const unsigned rr1[4] = {r1.x, r1.y, r1.z, r1.w};
        const unsigned rr2[4] = {r2.x, r2.y, r2.z, r2.w};
        #pragma unroll
        for (int i = 0; i < 4; ++i) {
            const h2 p0 = __builtin_bit_cast(h2, rr0[i]);
            const h2 p1 = __builtin_bit_cast(h2, rr1[i]);
            const h2 p2 = __builtin_bit_cast(h2, rr2[i]);
            const h2 y = a0[i] + p2;                    // y[t]
            m[i]  = __builtin_elementwise_max(m[i], y);
            a0[i] = a1[i] + p1;
            a1[i] = p0;
        }
    }
    // tail: y[32] = a0, y[33] = a1
    if (l < 13) {
        float mm[8];
        #pragma unroll
        for (int i = 0; i < 4; ++i) {
            const h2 v = __builtin_elementwise_max(m[i], __builtin_elementwise_max(a0[i], a1[i]));
            mm[2 * i]     = (float)v.x;
            mm[2 * i + 1] = (float)v.y;
        }
        const float4 b0 = *(const float4*)(conv_b + 8 * l);
        float* outc = out + (size_t)(tok0 + tl) * OUTD + 301 + 8 * l;
        outc[0] = tanhf(mm[0] + b0.x);
        outc[1] = tanhf(mm[1] + b0.y);
        outc[2] = tanhf(mm[2] + b0.z);
        outc[3] = tanhf(mm[3] + b0.w);
        if (l < 12) {
            const float4 b1 = *(const float4*)(conv_b + 8 * l + 4);
            outc[4] = tanhf(mm[4] + b1.x);
            outc[5] = tanhf(mm[5] + b1.y);
            outc[6] = tanhf(mm[6] + b1.z);
            outc[7] = tanhf(mm[7] + b1.w);
        }
    }
}

extern "C" void kernel_launch(void* const* d_in, const int* in_sizes, int n_in,
                              void* d_out, int out_size, void* d_ws, size_t ws_size,
                              hipStream_t stream) {
    const int*   input_word = (const int*)d_in[0];
    const int*   input_char = (const int*)d_in[1];
    const int*   input_pos  = (const int*)d_in[2];
    const float* word_table = (const float*)d_in[3];
    const float* char_table = (const float*)d_in[4];
    const float* pos_table  = (const float*)d_in[5];
    const float* conv_w     = (const float*)d_in[6];
    const float* conv_b     = (const float*)d_in[7];
    float* out = (float*)d_out;

    _Float16* P = (_Float16*)d_ws;                             // 76800 B

    precompute_P<<<dim3(NC, KK), 128, 0, stream>>>(conv_w, char_table, P);
    char_kernel<<<(BS * LS) / TPB, NTHR, 0, stream>>>(input_char, conv_b, P, out);
    copy_kernel<<<(BS * LS) / TPB, NTHR, 0, stream>>>(input_word, input_pos,
                                                      word_table, pos_table, out);
}

// Round 6
// 48.185 us; speedup vs baseline: 15.8948x; 15.8948x over previous
//
#include <hip/hip_runtime.h>
#include <hip/hip_fp16.h>

#define BS 64
#define LS 512
#define CL 32
#define WD 300
#define NC 100
#define CD 100
#define PD 100
#define NF 100
#define KK 3
#define OPAD 128                  // k-row padded to 128 f16 = 256 B = 8 full bank sweeps
#define PROW (KK*OPAD)            // 384 f16 = 768 B per char
#define PBYTES (NC*PROW*2)        // 76800 B
#define OUTD 501
#define TPB 64                    // tokens per block (both kernels)
#define NTHR 1024

typedef _Float16 h2 __attribute__((ext_vector_type(2)));

// ---------- Kernel 1: P[c][k][o] = sum_i conv_w[o,i,k] * char_table[c,i] (f16) ----------
__global__ void precompute_P(const float* __restrict__ conv_w,
                             const float* __restrict__ char_table,
                             _Float16* __restrict__ P) {
    const int c = blockIdx.x;      // 0..99
    const int k = blockIdx.y;      // 0..2
    const int o = threadIdx.x;     // 0..127
    __shared__ float row[CD];
    if (o < CD) row[o] = char_table[c * CD + o];
    __syncthreads();
    float acc = 0.f;
    if (o < NF) {
        const float* w = conv_w + o * (CD * KK) + k;
        #pragma unroll 4
        for (int i = 0; i < CD; ++i) acc += w[i * KK] * row[i];
    }
    P[(c * KK + k) * OPAD + o] = (_Float16)acc;    // o in [100,128) stores 0
}

// ---------- Kernel A: streaming copies (word + pos) + privacy distance ----------
__global__ __launch_bounds__(NTHR, 8) void copy_kernel(
        const int* __restrict__ input_word,
        const int* __restrict__ input_pos,
        const float* __restrict__ word_table,
        const float* __restrict__ pos_table,
        float* __restrict__ out) {
    __shared__ unsigned long long s_mask[LS / 64];      // 64 B
    const int tid  = threadIdx.x;
    const int tok0 = blockIdx.x * TPB;
    const int row  = tok0 >> 9;

    // privacy-mask ballot for this block's row
    if (tid < LS) {
        const int p = input_pos[row * LS + tid];
        const bool pm = (p == 3) | (p == 7) | (p == 11);
        const unsigned long long b = __ballot(pm);
        if ((tid & 63) == 0) s_mask[tid >> 6] = b;
    }

    // word: out[:, 1:301] — float4 gathers, scalar stores
    for (int i = tid; i < TPB * (WD / 4); i += NTHR) {
        const int t = i / (WD / 4);
        const int j = i - t * (WD / 4);
        const int w = input_word[tok0 + t];
        const float4 v = ((const float4*)word_table)[(size_t)w * (WD / 4) + j];
        float* o = out + (size_t)(tok0 + t) * OUTD + 1 + 4 * j;
        o[0] = v.x; o[1] = v.y; o[2] = v.z; o[3] = v.w;
    }
    // pos: out[:, 401:501]
    for (int i = tid; i < TPB * (PD / 4); i += NTHR) {
        const int t = i / (PD / 4);
        const int j = i - t * (PD / 4);
        const int p = input_pos[tok0 + t];
        const float4 v = ((const float4*)pos_table)[p * (PD / 4) + j];
        float* o = out + (size_t)(tok0 + t) * OUTD + 401 + 4 * j;
        o[0] = v.x; o[1] = v.y; o[2] = v.z; o[3] = v.w;
    }

    __syncthreads();

    // privacy distance: out[:, 0]
    if (tid < TPB) {
        const int j = (tok0 & (LS - 1)) + tid;
        const int wj = j >> 6, bj = j & 63;
        int last = -1000;
        {
            unsigned long long x = s_mask[wj] & ((2ull << bj) - 1ull);
            int w = wj;
            while (true) {
                if (x) { last = w * 64 + 63 - __clzll(x); break; }
                if (--w < 0) break;
                x = s_mask[w];
            }
        }
        int nxt = 1000;
        {
            unsigned long long x = s_mask[wj] & (~0ull << bj);
            int w = wj;
            while (true) {
                if (x) { nxt = w * 64 + (int)__ffsll((long long)x) - 1; break; }
                if (++w >= LS / 64) break;
                x = s_mask[w];
            }
        }
        out[(size_t)(tok0 + tid) * OUTD] = (float)min(j - last, nxt - j);
    }
}

// ---------- Kernel B: char CNN, conflict-free LDS layout, register-safe loop ----------
// 16 lanes per token; each lane owns 8 filters (16 B). Char bases are 768 B
// (bank-0 aligned) and each 16-lane group reads 256 B contiguous -> every
// ds_read_b128 covers all 32 banks exactly twice: zero bank conflicts.
// Char ids are re-read from LDS 4-at-a-time (broadcast) so no register array
// is ever runtime-indexed (rule #20), and outer unroll is capped at 2 so live
// ranges stay under the 64-VGPR launch-bounds cap (R5 spill post-mortem).
__global__ __launch_bounds__(NTHR, 8) void char_kernel(
        const int* __restrict__ input_char,
        const float* __restrict__ conv_b,
        const _Float16* __restrict__ Pg,
        float* __restrict__ out) {
    __shared__ alignas(16) _Float16 Pl[NC * PROW];         // 76800 B
    __shared__ alignas(16) unsigned char s_char[TPB * CL]; // 2048 B packed char ids

    const int tid  = threadIdx.x;
    const int tok0 = blockIdx.x * TPB;

    // stage P (4800 x 16B)
    {
        const uint4* src = (const uint4*)Pg;
        uint4* dst = (uint4*)Pl;
        for (int i = tid; i < PBYTES / 16; i += NTHR) dst[i] = src[i];
    }
    // stage char ids as packed bytes (512 dwords)
    if (tid < (TPB * CL) / 4) {
        const int4 c4 = ((const int4*)(input_char + tok0 * CL))[tid];
        ((unsigned*)s_char)[tid] =
            (unsigned)c4.x | ((unsigned)c4.y << 8) | ((unsigned)c4.z << 16) | ((unsigned)c4.w << 24);
    }
    __syncthreads();

    const int tl = tid >> 4;        // token in block (0..63)
    const int l  = tid & 15;        // lane-in-token = filter octet (0..15)

    const unsigned* s_cw = (const unsigned*)s_char;
    const char* Pb = (const char*)Pl + l * 16;
    h2 a0[4], a1[4], m[4];
    #pragma unroll
    for (int i = 0; i < 4; ++i) {
        a0[i] = (h2)(_Float16)0;
        a1[i] = (h2)(_Float16)0;
        m[i]  = (h2)(_Float16)(-60000.f);
    }
    #pragma unroll 2
    for (int w = 0; w < CL / 4; ++w) {
        const unsigned wd = s_cw[tl * (CL / 4) + w];   // 4 packed char ids, broadcast
        #pragma unroll
        for (int b = 0; b < 4; ++b) {
            const int ca = (int)((wd >> (8 * b)) & 0xFFu) * (PROW * 2);
            const uint4 r0 = *(const uint4*)(Pb + ca + 0 * (OPAD * 2));
            const uint4 r1 = *(const uint4*)(Pb + ca + 1 * (OPAD * 2));
            const uint4 r2 = *(const uint4*)(Pb + ca + 2 * (OPAD * 2));
            #pragma unroll
            for (int i = 0; i < 4; ++i) {
                const unsigned c0 = (i == 0) ? r0.x : (i == 1) ? r0.y : (i == 2) ? r0.z : r0.w;
                const unsigned c1 = (i == 0) ? r1.x : (i == 1) ? r1.y : (i == 2) ? r1.z : r1.w;
                const unsigned c2 = (i == 0) ? r2.x : (i == 1) ? r2.y : (i == 2) ? r2.z : r2.w;
                const h2 p0 = __builtin_bit_cast(h2, c0);
                const h2 p1 = __builtin_bit_cast(h2, c1);
                const h2 p2 = __builtin_bit_cast(h2, c2);
                const h2 y = a0[i] + p2;                    // y[t]
                m[i]  = __builtin_elementwise_max(m[i], y);
                a0[i] = a1[i] + p1;
                a1[i] = p0;
            }
        }
    }
    // tail: y[32] = a0, y[33] = a1
    if (l < 13) {
        float mm[8];
        #pragma unroll
        for (int i = 0; i < 4; ++i) {
            const h2 v = __builtin_elementwise_max(m[i], __builtin_elementwise_max(a0[i], a1[i]));
            mm[2 * i]     = (float)v.x;
            mm[2 * i + 1] = (float)v.y;
        }
        const float4 b0 = *(const float4*)(conv_b + 8 * l);
        float* outc = out + (size_t)(tok0 + tl) * OUTD + 301 + 8 * l;
        outc[0] = tanhf(mm[0] + b0.x);
        outc[1] = tanhf(mm[1] + b0.y);
        outc[2] = tanhf(mm[2] + b0.z);
        outc[3] = tanhf(mm[3] + b0.w);
        if (l < 12) {
            const float4 b1 = *(const float4*)(conv_b + 8 * l + 4);
            outc[4] = tanhf(mm[4] + b1.x);
            outc[5] = tanhf(mm[5] + b1.y);
            outc[6] = tanhf(mm[6] + b1.z);
            outc[7] = tanhf(mm[7] + b1.w);
        }
    }
}

extern "C" void kernel_launch(void* const* d_in, const int* in_sizes, int n_in,
                              void* d_out, int out_size, void* d_ws, size_t ws_size,
                              hipStream_t stream) {
    const int*   input_word = (const int*)d_in[0];
    const int*   input_char = (const int*)d_in[1];
    const int*   input_pos  = (const int*)d_in[2];
    const float* word_table = (const float*)d_in[3];
    const float* char_table = (const float*)d_in[4];
    const float* pos_table  = (const float*)d_in[5];
    const float* conv_w     = (const float*)d_in[6];
    const float* conv_b     = (const float*)d_in[7];
    float* out = (float*)d_out;

    _Float16* P = (_Float16*)d_ws;                             // 76800 B

    precompute_P<<<dim3(NC, KK), 128, 0, stream>>>(conv_w, char_table, P);
    char_kernel<<<(BS * LS) / TPB, NTHR, 0, stream>>>(input_char, conv_b, P, out);
    copy_kernel<<<(BS * LS) / TPB, NTHR, 0, stream>>>(input_word, input_pos,
                                                      word_table, pos_table, out);
}

// Round 7
// 43.004 us; speedup vs baseline: 17.8100x; 1.1205x over previous
//
#include <hip/hip_runtime.h>
#include <hip/hip_fp16.h>

#define BS 64
#define LS 512
#define CL 32
#define WD 300
#define NC 100
#define CD 100
#define PD 100
#define NF 100
#define KK 3
#define OPAD 128                  // k-row padded to 128 f16 = 256 B = 8 full bank sweeps
#define PROW (KK*OPAD)            // 384 f16 = 768 B per char
#define PBYTES (NC*PROW*2)        // 76800 B
#define OUTD 501
#define TPB 64                    // tokens per block-unit
#define NTHR 1024

typedef _Float16 h2 __attribute__((ext_vector_type(2)));

// ---------- Kernel 1: P[c][k][o] = sum_i conv_w[o,i,k] * char_table[c,i] (f16) ----------
__global__ void precompute_P(const float* __restrict__ conv_w,
                             const float* __restrict__ char_table,
                             _Float16* __restrict__ P) {
    const int c = blockIdx.x;      // 0..99
    const int k = blockIdx.y;      // 0..2
    const int o = threadIdx.x;     // 0..127
    __shared__ float row[CD];
    if (o < CD) row[o] = char_table[c * CD + o];
    __syncthreads();
    float acc = 0.f;
    if (o < NF) {
        const float* w = conv_w + o * (CD * KK) + k;
        #pragma unroll 4
        for (int i = 0; i < CD; ++i) acc += w[i * KK] * row[i];
    }
    P[(c * KK + k) * OPAD + o] = (_Float16)acc;    // o in [100,128) stores 0
}

// ---------- Kernel 2: grid-specialized main kernel ----------
// Even blocks: char CNN (LDS-pipe-bound). Odd blocks: word/pos/dist streaming
// (HBM-bound). Interleaved so each CU co-hosts one of each and both pipes run
// concurrently. Disjoint output columns -> no inter-block dependencies.
__global__ __launch_bounds__(NTHR, 8) void main_kernel(
        const int* __restrict__ input_word,
        const int* __restrict__ input_char,
        const int* __restrict__ input_pos,
        const float* __restrict__ word_table,
        const float* __restrict__ pos_table,
        const float* __restrict__ conv_b,
        const _Float16* __restrict__ Pg,
        float* __restrict__ out) {
    __shared__ alignas(16) _Float16 Pl[NC * PROW];         // 76800 B
    __shared__ alignas(16) unsigned char s_char[TPB * CL]; // 2048 B (aliases s_mask usage ok: disjoint roles)
    __shared__ unsigned long long s_mask[LS / 64];         // 64 B

    const int tid  = threadIdx.x;
    const int unit = blockIdx.x >> 1;
    const int tok0 = unit * TPB;

    if ((blockIdx.x & 1) == 0) {
        // ================== CHAR-CNN ROLE ==================
        // stage P (4800 x 16B)
        {
            const uint4* src = (const uint4*)Pg;
            uint4* dst = (uint4*)Pl;
            for (int i = tid; i < PBYTES / 16; i += NTHR) dst[i] = src[i];
        }
        // stage char ids as packed bytes (512 dwords)
        if (tid < (TPB * CL) / 4) {
            const int4 c4 = ((const int4*)(input_char + tok0 * CL))[tid];
            ((unsigned*)s_char)[tid] =
                (unsigned)c4.x | ((unsigned)c4.y << 8) | ((unsigned)c4.z << 16) | ((unsigned)c4.w << 24);
        }
        __syncthreads();

        const int tl = tid >> 4;        // token in block (0..63)
        const int l  = tid & 15;        // lane-in-token = filter octet (0..15)

        const unsigned* s_cw = (const unsigned*)s_char;
        const char* Pb = (const char*)Pl + l * 16;
        h2 a0[4], a1[4], m[4];
        #pragma unroll
        for (int i = 0; i < 4; ++i) {
            a0[i] = (h2)(_Float16)0;
            a1[i] = (h2)(_Float16)0;
            m[i]  = (h2)(_Float16)(-60000.f);
        }
        #pragma unroll 2
        for (int w = 0; w < CL / 4; ++w) {
            const unsigned wd = s_cw[tl * (CL / 4) + w];   // 4 packed char ids, broadcast
            #pragma unroll
            for (int b = 0; b < 4; ++b) {
                const int ca = (int)((wd >> (8 * b)) & 0xFFu) * (PROW * 2);
                const uint4 r0 = *(const uint4*)(Pb + ca + 0 * (OPAD * 2));
                const uint4 r1 = *(const uint4*)(Pb + ca + 1 * (OPAD * 2));
                const uint4 r2 = *(const uint4*)(Pb + ca + 2 * (OPAD * 2));
                #pragma unroll
                for (int i = 0; i < 4; ++i) {
                    const unsigned c0 = (i == 0) ? r0.x : (i == 1) ? r0.y : (i == 2) ? r0.z : r0.w;
                    const unsigned c1 = (i == 0) ? r1.x : (i == 1) ? r1.y : (i == 2) ? r1.z : r1.w;
                    const unsigned c2 = (i == 0) ? r2.x : (i == 1) ? r2.y : (i == 2) ? r2.z : r2.w;
                    const h2 p0 = __builtin_bit_cast(h2, c0);
                    const h2 p1 = __builtin_bit_cast(h2, c1);
                    const h2 p2 = __builtin_bit_cast(h2, c2);
                    const h2 y = a0[i] + p2;                    // y[t]
                    m[i]  = __builtin_elementwise_max(m[i], y);
                    a0[i] = a1[i] + p1;
                    a1[i] = p0;
                }
            }
        }
        // tail: y[32] = a0, y[33] = a1
        if (l < 13) {
            float mm[8];
            #pragma unroll
            for (int i = 0; i < 4; ++i) {
                const h2 v = __builtin_elementwise_max(m[i], __builtin_elementwise_max(a0[i], a1[i]));
                mm[2 * i]     = (float)v.x;
                mm[2 * i + 1] = (float)v.y;
            }
            const float4 b0 = *(const float4*)(conv_b + 8 * l);
            float* outc = out + (size_t)(tok0 + tl) * OUTD + 301 + 8 * l;
            outc[0] = tanhf(mm[0] + b0.x);
            outc[1] = tanhf(mm[1] + b0.y);
            outc[2] = tanhf(mm[2] + b0.z);
            outc[3] = tanhf(mm[3] + b0.w);
            if (l < 12) {
                const float4 b1 = *(const float4*)(conv_b + 8 * l + 4);
                outc[4] = tanhf(mm[4] + b1.x);
                outc[5] = tanhf(mm[5] + b1.y);
                outc[6] = tanhf(mm[6] + b1.z);
                outc[7] = tanhf(mm[7] + b1.w);
            }
        }
    } else {
        // ================== STREAMING-COPY ROLE ==================
        const int row = tok0 >> 9;

        // privacy-mask ballot for this block's row
        if (tid < LS) {
            const int p = input_pos[row * LS + tid];
            const bool pm = (p == 3) | (p == 7) | (p == 11);
            const unsigned long long b = __ballot(pm);
            if ((tid & 63) == 0) s_mask[tid >> 6] = b;
        }

        // word: out[:, 1:301] — float4 gathers, scalar stores
        for (int i = tid; i < TPB * (WD / 4); i += NTHR) {
            const int t = i / (WD / 4);
            const int j = i - t * (WD / 4);
            const int w = input_word[tok0 + t];
            const float4 v = ((const float4*)word_table)[(size_t)w * (WD / 4) + j];
            float* o = out + (size_t)(tok0 + t) * OUTD + 1 + 4 * j;
            o[0] = v.x; o[1] = v.y; o[2] = v.z; o[3] = v.w;
        }
        // pos: out[:, 401:501]
        for (int i = tid; i < TPB * (PD / 4); i += NTHR) {
            const int t = i / (PD / 4);
            const int j = i - t * (PD / 4);
            const int p = input_pos[tok0 + t];
            const float4 v = ((const float4*)pos_table)[p * (PD / 4) + j];
            float* o = out + (size_t)(tok0 + t) * OUTD + 401 + 4 * j;
            o[0] = v.x; o[1] = v.y; o[2] = v.z; o[3] = v.w;
        }

        __syncthreads();

        // privacy distance: out[:, 0]
        if (tid < TPB) {
            const int j = (tok0 & (LS - 1)) + tid;
            const int wj = j >> 6, bj = j & 63;
            int last = -1000;
            {
                unsigned long long x = s_mask[wj] & ((2ull << bj) - 1ull);
                int w = wj;
                while (true) {
                    if (x) { last = w * 64 + 63 - __clzll(x); break; }
                    if (--w < 0) break;
                    x = s_mask[w];
                }
            }
            int nxt = 1000;
            {
                unsigned long long x = s_mask[wj] & (~0ull << bj);
                int w = wj;
                while (true) {
                    if (x) { nxt = w * 64 + (int)__ffsll((long long)x) - 1; break; }
                    if (++w >= LS / 64) break;
                    x = s_mask[w];
                }
            }
            out[(size_t)(tok0 + tid) * OUTD] = (float)min(j - last, nxt - j);
        }
    }
}

extern "C" void kernel_launch(void* const* d_in, const int* in_sizes, int n_in,
                              void* d_out, int out_size, void* d_ws, size_t ws_size,
                              hipStream_t stream) {
    const int*   input_word = (const int*)d_in[0];
    const int*   input_char = (const int*)d_in[1];
    const int*   input_pos  = (const int*)d_in[2];
    const float* word_table = (const float*)d_in[3];
    const float* char_table = (const float*)d_in[4];
    const float* pos_table  = (const float*)d_in[5];
    const float* conv_w     = (const float*)d_in[6];
    const float* conv_b     = (const float*)d_in[7];
    float* out = (float*)d_out;

    _Float16* P = (_Float16*)d_ws;                             // 76800 B

    precompute_P<<<dim3(NC, KK), 128, 0, stream>>>(conv_w, char_table, P);
    main_kernel<<<2 * (BS * LS) / TPB, NTHR, 0, stream>>>(
        input_word, input_char, input_pos, word_table, pos_table, conv_b, P, out);
}

// Round 8
// 42.651 us; speedup vs baseline: 17.9572x; 1.0083x over previous
//
#include <hip/hip_runtime.h>
#include <hip/hip_fp16.h>

#define BS 64
#define LS 512
#define CL 32
#define WD 300
#define NC 100
#define CD 100
#define PD 100
#define NF 100
#define KK 3
#define OPAD 128                  // k-row padded to 128 f16 = 256 B = 8 full bank sweeps
#define PROW (KK*OPAD)            // 384 f16 = 768 B per char
#define PBYTES (NC*PROW*2)        // 76800 B
#define NV4 (PBYTES/16)           // 4800 uint4
#define OUTD 501
#define TPB 64                    // tokens per block
#define NTHR 1024

typedef _Float16 h2 __attribute__((ext_vector_type(2)));

// ---------- Kernel 1: P[c][k][o] = sum_i conv_w[o,i,k] * char_table[c,i] (f16) ----------
__global__ void precompute_P(const float* __restrict__ conv_w,
                             const float* __restrict__ char_table,
                             _Float16* __restrict__ P) {
    const int c = blockIdx.x;      // 0..99
    const int k = blockIdx.y;      // 0..2
    const int o = threadIdx.x;     // 0..127
    __shared__ float row[CD];
    if (o < CD) row[o] = char_table[c * CD + o];
    __syncthreads();
    float acc = 0.f;
    if (o < NF) {
        const float* w = conv_w + o * (CD * KK) + k;
        #pragma unroll 4
        for (int i = 0; i < CD; ++i) acc += w[i * KK] * row[i];
    }
    P[(c * KK + k) * OPAD + o] = (_Float16)acc;    // o in [100,128) stores 0
}

// ---------- Kernel 2: fully fused, per-block overlapped ----------
// Per block (64 tokens): issue P-staging loads early -> ballot/char-pack ->
// word copy (HBM streaming hides staging latency) -> LDS-write P -> barrier ->
// zero-conflict char loop -> pos copy + dist. Both pipes (HBM, LDS) busy
// within every block; identical blocks -> no role imbalance.
__global__ __launch_bounds__(NTHR, 8) void main_kernel(
        const int* __restrict__ input_word,
        const int* __restrict__ input_char,
        const int* __restrict__ input_pos,
        const float* __restrict__ word_table,
        const float* __restrict__ pos_table,
        const float* __restrict__ conv_b,
        const _Float16* __restrict__ Pg,
        float* __restrict__ out) {
    __shared__ alignas(16) _Float16 Pl[NC * PROW];         // 76800 B
    __shared__ alignas(16) unsigned char s_char[TPB * CL]; // 2048 B packed char ids
    __shared__ unsigned long long s_mask[LS / 64];         // 64 B   (total 80960 B -> 2 blocks/CU)

    const int tid  = threadIdx.x;
    const int tok0 = blockIdx.x * TPB;

    // ---- 1. issue P staging loads (held in regs; latency hidden by steps 2-4) ----
    const uint4* src = (const uint4*)Pg;
    const uint4 s0 = src[tid];
    const uint4 s1 = src[tid + NTHR];
    const uint4 s2 = src[tid + 2 * NTHR];
    const uint4 s3 = src[tid + 3 * NTHR];
    uint4 s4 = {};
    const bool h4 = (tid + 4 * NTHR) < NV4;    // tid < 704
    if (h4) s4 = src[tid + 4 * NTHR];

    // ---- 2. privacy-mask ballot for this block's row ----
    const int row = tok0 >> 9;
    if (tid < LS) {
        const int p = input_pos[row * LS + tid];
        const bool pm = (p == 3) | (p == 7) | (p == 11);
        const unsigned long long b = __ballot(pm);
        if ((tid & 63) == 0) s_mask[tid >> 6] = b;
    }

    // ---- 3. stage char ids as packed bytes (512 dwords) ----
    if (tid < (TPB * CL) / 4) {
        const int4 c4 = ((const int4*)(input_char + tok0 * CL))[tid];
        ((unsigned*)s_char)[tid] =
            (unsigned)c4.x | ((unsigned)c4.y << 8) | ((unsigned)c4.z << 16) | ((unsigned)c4.w << 24);
    }

    // ---- 4. word copy: out[:, 1:301] (float4 gathers; overlaps staging latency) ----
    for (int i = tid; i < TPB * (WD / 4); i += NTHR) {
        const int t = i / (WD / 4);
        const int j = i - t * (WD / 4);
        const int w = input_word[tok0 + t];
        const float4 v = ((const float4*)word_table)[(size_t)w * (WD / 4) + j];
        float* o = out + (size_t)(tok0 + t) * OUTD + 1 + 4 * j;
        o[0] = v.x; o[1] = v.y; o[2] = v.z; o[3] = v.w;
    }

    // ---- 5. write staged P to LDS, barrier ----
    {
        uint4* dst = (uint4*)Pl;
        dst[tid] = s0;
        dst[tid + NTHR] = s1;
        dst[tid + 2 * NTHR] = s2;
        dst[tid + 3 * NTHR] = s3;
        if (h4) dst[tid + 4 * NTHR] = s4;
    }
    __syncthreads();

    // ---- 6. char CNN: 16 lanes/token, 8 filters each, zero bank conflicts ----
    const int tl = tid >> 4;        // token in block (0..63)
    const int l  = tid & 15;        // lane-in-token = filter octet (0..15)
    const unsigned* s_cw = (const unsigned*)s_char;
    const char* Pb = (const char*)Pl + l * 16;
    h2 a0[4], a1[4], m[4];
    #pragma unroll
    for (int i = 0; i < 4; ++i) {
        a0[i] = (h2)(_Float16)0;
        a1[i] = (h2)(_Float16)0;
        m[i]  = (h2)(_Float16)(-60000.f);
    }
    #pragma unroll 2
    for (int w = 0; w < CL / 4; ++w) {
        const unsigned wd = s_cw[tl * (CL / 4) + w];   // 4 packed char ids, broadcast
        #pragma unroll
        for (int b = 0; b < 4; ++b) {
            const int ca = (int)((wd >> (8 * b)) & 0xFFu) * (PROW * 2);
            const uint4 r0 = *(const uint4*)(Pb + ca + 0 * (OPAD * 2));
            const uint4 r1 = *(const uint4*)(Pb + ca + 1 * (OPAD * 2));
            const uint4 r2 = *(const uint4*)(Pb + ca + 2 * (OPAD * 2));
            #pragma unroll
            for (int i = 0; i < 4; ++i) {
                const unsigned c0 = (i == 0) ? r0.x : (i == 1) ? r0.y : (i == 2) ? r0.z : r0.w;
                const unsigned c1 = (i == 0) ? r1.x : (i == 1) ? r1.y : (i == 2) ? r1.z : r1.w;
                const unsigned c2 = (i == 0) ? r2.x : (i == 1) ? r2.y : (i == 2) ? r2.z : r2.w;
                const h2 p0 = __builtin_bit_cast(h2, c0);
                const h2 p1 = __builtin_bit_cast(h2, c1);
                const h2 p2 = __builtin_bit_cast(h2, c2);
                const h2 y = a0[i] + p2;                    // y[t]
                m[i]  = __builtin_elementwise_max(m[i], y);
                a0[i] = a1[i] + p1;
                a1[i] = p0;
            }
        }
    }
    // tail: y[32] = a0, y[33] = a1; epilogue stores cols 301-400
    if (l < 13) {
        float mm[8];
        #pragma unroll
        for (int i = 0; i < 4; ++i) {
            const h2 v = __builtin_elementwise_max(m[i], __builtin_elementwise_max(a0[i], a1[i]));
            mm[2 * i]     = (float)v.x;
            mm[2 * i + 1] = (float)v.y;
        }
        const float4 b0 = *(const float4*)(conv_b + 8 * l);
        float* outc = out + (size_t)(tok0 + tl) * OUTD + 301 + 8 * l;
        outc[0] = tanhf(mm[0] + b0.x);
        outc[1] = tanhf(mm[1] + b0.y);
        outc[2] = tanhf(mm[2] + b0.z);
        outc[3] = tanhf(mm[3] + b0.w);
        if (l < 12) {
            const float4 b1 = *(const float4*)(conv_b + 8 * l + 4);
            outc[4] = tanhf(mm[4] + b1.x);
            outc[5] = tanhf(mm[5] + b1.y);
            outc[6] = tanhf(mm[6] + b1.z);
            outc[7] = tanhf(mm[7] + b1.w);
        }
    }

    // ---- 7. pos copy: out[:, 401:501] ----
    for (int i = tid; i < TPB * (PD / 4); i += NTHR) {
        const int t = i / (PD / 4);
        const int j = i - t * (PD / 4);
        const int p = input_pos[tok0 + t];
        const float4 v = ((const float4*)pos_table)[p * (PD / 4) + j];
        float* o = out + (size_t)(tok0 + t) * OUTD + 401 + 4 * j;
        o[0] = v.x; o[1] = v.y; o[2] = v.z; o[3] = v.w;
    }

    // ---- 8. privacy distance: out[:, 0] ----
    if (tid < TPB) {
        const int j = (tok0 & (LS - 1)) + tid;
        const int wj = j >> 6, bj = j & 63;
        int last = -1000;
        {
            unsigned long long x = s_mask[wj] & ((2ull << bj) - 1ull);
            int w = wj;
            while (true) {
                if (x) { last = w * 64 + 63 - __clzll(x); break; }
                if (--w < 0) break;
                x = s_mask[w];
            }
        }
        int nxt = 1000;
        {
            unsigned long long x = s_mask[wj] & (~0ull << bj);
            int w = wj;
            while (true) {
                if (x) { nxt = w * 64 + (int)__ffsll((long long)x) - 1; break; }
                if (++w >= LS / 64) break;
                x = s_mask[w];
            }
        }
        out[(size_t)(tok0 + tid) * OUTD] = (float)min(j - last, nxt - j);
    }
}

extern "C" void kernel_launch(void* const* d_in, const int* in_sizes, int n_in,
                              void* d_out, int out_size, void* d_ws, size_t ws_size,
                              hipStream_t stream) {
    const int*   input_word = (const int*)d_in[0];
    const int*   input_char = (const int*)d_in[1];
    const int*   input_pos  = (const int*)d_in[2];
    const float* word_table = (const float*)d_in[3];
    const float* char_table = (const float*)d_in[4];
    const float* pos_table  = (const float*)d_in[5];
    const float* conv_w     = (const float*)d_in[6];
    const float* conv_b     = (const float*)d_in[7];
    float* out = (float*)d_out;

    _Float16* P = (_Float16*)d_ws;                             // 76800 B

    precompute_P<<<dim3(NC, KK), 128, 0, stream>>>(conv_w, char_table, P);
    main_kernel<<<(BS * LS) / TPB, NTHR, 0, stream>>>(
        input_word, input_char, input_pos, word_table, pos_table, conv_b, P, out);
}

// Round 9
// 42.600 us; speedup vs baseline: 17.9787x; 1.0012x over previous
//
#include <hip/hip_runtime.h>
#include <hip/hip_fp16.h>

#define BS 64
#define LS 512
#define CL 32
#define WD 300
#define NC 100
#define CD 100
#define PD 100
#define NF 100
#define KK 3
#define OPAD 128                  // k-row padded to 128 f16 = 256 B = 8 full bank sweeps
#define PROW (KK*OPAD)            // 384 f16 = 768 B per char
#define PBYTES (NC*PROW*2)        // 76800 B
#define NV4 (PBYTES/16)           // 4800 uint4
#define OUTD 501
#define TPB 64                    // tokens per block
#define NTHR 1024

typedef _Float16 h2 __attribute__((ext_vector_type(2)));

// ---------- Kernel 1: P[c][k][o] = sum_i conv_w[o,i,k] * char_table[c,i] (f16) ----------
__global__ void precompute_P(const float* __restrict__ conv_w,
                             const float* __restrict__ char_table,
                             _Float16* __restrict__ P) {
    const int c = blockIdx.x;      // 0..99
    const int k = blockIdx.y;      // 0..2
    const int o = threadIdx.x;     // 0..127
    __shared__ float row[CD];
    if (o < CD) row[o] = char_table[c * CD + o];
    __syncthreads();
    float acc = 0.f;
    if (o < NF) {
        const float* w = conv_w + o * (CD * KK) + k;
        #pragma unroll 4
        for (int i = 0; i < CD; ++i) acc += w[i * KK] * row[i];
    }
    P[(c * KK + k) * OPAD + o] = (_Float16)acc;    // o in [100,128) stores 0
}

// ---------- Kernel 2: fully fused, per-block overlapped ----------
// Per block (64 tokens): issue P-staging loads early -> ballot/char-pack ->
// word copy (HBM streaming hides staging latency) -> LDS-write P -> barrier ->
// zero-conflict char loop -> pos copy + dist. Both pipes (HBM, LDS) busy
// within every block; identical blocks -> no role imbalance.
__global__ __launch_bounds__(NTHR, 8) void main_kernel(
        const int* __restrict__ input_word,
        const int* __restrict__ input_char,
        const int* __restrict__ input_pos,
        const float* __restrict__ word_table,
        const float* __restrict__ pos_table,
        const float* __restrict__ conv_b,
        const _Float16* __restrict__ Pg,
        float* __restrict__ out) {
    __shared__ alignas(16) _Float16 Pl[NC * PROW];         // 76800 B
    __shared__ alignas(16) unsigned char s_char[TPB * CL]; // 2048 B packed char ids
    __shared__ unsigned long long s_mask[LS / 64];         // 64 B   (total 80960 B -> 2 blocks/CU)

    const int tid  = threadIdx.x;
    const int tok0 = blockIdx.x * TPB;

    // ---- 1. issue P staging loads (held in regs; latency hidden by steps 2-4) ----
    const uint4* src = (const uint4*)Pg;
    const uint4 s0 = src[tid];
    const uint4 s1 = src[tid + NTHR];
    const uint4 s2 = src[tid + 2 * NTHR];
    const uint4 s3 = src[tid + 3 * NTHR];
    uint4 s4 = {};
    const bool h4 = (tid + 4 * NTHR) < NV4;    // tid < 704
    if (h4) s4 = src[tid + 4 * NTHR];

    // ---- 2. privacy-mask ballot for this block's row ----
    const int row = tok0 >> 9;
    if (tid < LS) {
        const int p = input_pos[row * LS + tid];
        const bool pm = (p == 3) | (p == 7) | (p == 11);
        const unsigned long long b = __ballot(pm);
        if ((tid & 63) == 0) s_mask[tid >> 6] = b;
    }

    // ---- 3. stage char ids as packed bytes (512 dwords) ----
    if (tid < (TPB * CL) / 4) {
        const int4 c4 = ((const int4*)(input_char + tok0 * CL))[tid];
        ((unsigned*)s_char)[tid] =
            (unsigned)c4.x | ((unsigned)c4.y << 8) | ((unsigned)c4.z << 16) | ((unsigned)c4.w << 24);
    }

    // ---- 4. word copy: out[:, 1:301] (float4 gathers; overlaps staging latency) ----
    for (int i = tid; i < TPB * (WD / 4); i += NTHR) {
        const int t = i / (WD / 4);
        const int j = i - t * (WD / 4);
        const int w = input_word[tok0 + t];
        const float4 v = ((const float4*)word_table)[(size_t)w * (WD / 4) + j];
        float* o = out + (size_t)(tok0 + t) * OUTD + 1 + 4 * j;
        o[0] = v.x; o[1] = v.y; o[2] = v.z; o[3] = v.w;
    }

    // ---- 5. write staged P to LDS, barrier ----
    {
        uint4* dst = (uint4*)Pl;
        dst[tid] = s0;
        dst[tid + NTHR] = s1;
        dst[tid + 2 * NTHR] = s2;
        dst[tid + 3 * NTHR] = s3;
        if (h4) dst[tid + 4 * NTHR] = s4;
    }
    __syncthreads();

    // ---- 6. char CNN: 16 lanes/token, 8 filters each, zero bank conflicts ----
    const int tl = tid >> 4;        // token in block (0..63)
    const int l  = tid & 15;        // lane-in-token = filter octet (0..15)
    const unsigned* s_cw = (const unsigned*)s_char;
    const char* Pb = (const char*)Pl + l * 16;
    h2 a0[4], a1[4], m[4];
    #pragma unroll
    for (int i = 0; i < 4; ++i) {
        a0[i] = (h2)(_Float16)0;
        a1[i] = (h2)(_Float16)0;
        m[i]  = (h2)(_Float16)(-60000.f);
    }
    #pragma unroll 2
    for (int w = 0; w < CL / 4; ++w) {
        const unsigned wd = s_cw[tl * (CL / 4) + w];   // 4 packed char ids, broadcast
        #pragma unroll
        for (int b = 0; b < 4; ++b) {
            const int ca = (int)((wd >> (8 * b)) & 0xFFu) * (PROW * 2);
            const uint4 r0 = *(const uint4*)(Pb + ca + 0 * (OPAD * 2));
            const uint4 r1 = *(const uint4*)(Pb + ca + 1 * (OPAD * 2));
            const uint4 r2 = *(const uint4*)(Pb + ca + 2 * (OPAD * 2));
            #pragma unroll
            for (int i = 0; i < 4; ++i) {
                const unsigned c0 = (i == 0) ? r0.x : (i == 1) ? r0.y : (i == 2) ? r0.z : r0.w;
                const unsigned c1 = (i == 0) ? r1.x : (i == 1) ? r1.y : (i == 2) ? r1.z : r1.w;
                const unsigned c2 = (i == 0) ? r2.x : (i == 1) ? r2.y : (i == 2) ? r2.z : r2.w;
                const h2 p0 = __builtin_bit_cast(h2, c0);
                const h2 p1 = __builtin_bit_cast(h2, c1);
                const h2 p2 = __builtin_bit_cast(h2, c2);
                const h2 y = a0[i] + p2;                    // y[t]
                m[i]  = __builtin_elementwise_max(m[i], y);
                a0[i] = a1[i] + p1;
                a1[i] = p0;
            }
        }
    }
    // tail: y[32] = a0, y[33] = a1; epilogue stores cols 301-400
    if (l < 13) {
        float mm[8];
        #pragma unroll
        for (int i = 0; i < 4; ++i) {
            const h2 v = __builtin_elementwise_max(m[i], __builtin_elementwise_max(a0[i], a1[i]));
            mm[2 * i]     = (float)v.x;
            mm[2 * i + 1] = (float)v.y;
        }
        const float4 b0 = *(const float4*)(conv_b + 8 * l);
        float* outc = out + (size_t)(tok0 + tl) * OUTD + 301 + 8 * l;
        outc[0] = tanhf(mm[0] + b0.x);
        outc[1] = tanhf(mm[1] + b0.y);
        outc[2] = tanhf(mm[2] + b0.z);
        outc[3] = tanhf(mm[3] + b0.w);
        if (l < 12) {
            const float4 b1 = *(const float4*)(conv_b + 8 * l + 4);
            outc[4] = tanhf(mm[4] + b1.x);
            outc[5] = tanhf(mm[5] + b1.y);
            outc[6] = tanhf(mm[6] + b1.z);
            outc[7] = tanhf(mm[7] + b1.w);
        }
    }

    // ---- 7. pos copy: out[:, 401:501] ----
    for (int i = tid; i < TPB * (PD / 4); i += NTHR) {
        const int t = i / (PD / 4);
        const int j = i - t * (PD / 4);
        const int p = input_pos[tok0 + t];
        const float4 v = ((const float4*)pos_table)[p * (PD / 4) + j];
        float* o = out + (size_t)(tok0 + t) * OUTD + 401 + 4 * j;
        o[0] = v.x; o[1] = v.y; o[2] = v.z; o[3] = v.w;
    }

    // ---- 8. privacy distance: out[:, 0] ----
    if (tid < TPB) {
        const int j = (tok0 & (LS - 1)) + tid;
        const int wj = j >> 6, bj = j & 63;
        int last = -1000;
        {
            unsigned long long x = s_mask[wj] & ((2ull << bj) - 1ull);
            int w = wj;
            while (true) {
                if (x) { last = w * 64 + 63 - __clzll(x); break; }
                if (--w < 0) break;
                x = s_mask[w];
            }
        }
        int nxt = 1000;
        {
            unsigned long long x = s_mask[wj] & (~0ull << bj);
            int w = wj;
            while (true) {
                if (x) { nxt = w * 64 + (int)__ffsll((long long)x) - 1; break; }
                if (++w >= LS / 64) break;
                x = s_mask[w];
            }
        }
        out[(size_t)(tok0 + tid) * OUTD] = (float)min(j - last, nxt - j);
    }
}

extern "C" void kernel_launch(void* const* d_in, const int* in_sizes, int n_in,
                              void* d_out, int out_size, void* d_ws, size_t ws_size,
                              hipStream_t stream) {
    const int*   input_word = (const int*)d_in[0];
    const int*   input_char = (const int*)d_in[1];
    const int*   input_pos  = (const int*)d_in[2];
    const float* word_table = (const float*)d_in[3];
    const float* char_table = (const float*)d_in[4];
    const float* pos_table  = (const float*)d_in[5];
    const float* conv_w     = (const float*)d_in[6];
    const float* conv_b     = (const float*)d_in[7];
    float* out = (float*)d_out;

    _Float16* P = (_Float16*)d_ws;                             // 76800 B

    precompute_P<<<dim3(NC, KK), 128, 0, stream>>>(conv_w, char_table, P);
    main_kernel<<<(BS * LS) / TPB, NTHR, 0, stream>>>(
        input_word, input_char, input_pos, word_table, pos_table, conv_b, P, out);
}

// Round 10
// 38.904 us; speedup vs baseline: 19.6869x; 1.0950x over previous
//
#include <hip/hip_runtime.h>
#include <hip/hip_fp16.h>

#define BS 64
#define LS 512
#define CL 32
#define WD 300
#define NC 100
#define CD 100
#define PD 100
#define NF 100
#define KK 3
#define OPAD 128                  // k-row padded to 128 f16 = 256 B = 8 full bank sweeps
#define PROW (KK*OPAD)            // 384 f16 = 768 B per char
#define PBYTES (NC*PROW*2)        // 76800 B
#define NV4 (PBYTES/16)           // 4800 uint4
#define OUTD 501
#define TPB 64                    // tokens per block
#define NTHR 1024

typedef _Float16 h2 __attribute__((ext_vector_type(2)));

// ---------- Kernel 1: P[c][k][o] = sum_i conv_w[o,i,k] * char_table[c,i] (f16) ----------
__global__ void precompute_P(const float* __restrict__ conv_w,
                             const float* __restrict__ char_table,
                             _Float16* __restrict__ P) {
    const int c = blockIdx.x;      // 0..99
    const int k = blockIdx.y;      // 0..2
    const int o = threadIdx.x;     // 0..127
    __shared__ float row[CD];
    if (o < CD) row[o] = char_table[c * CD + o];
    __syncthreads();
    float acc = 0.f;
    if (o < NF) {
        const float* w = conv_w + o * (CD * KK) + k;
        #pragma unroll 4
        for (int i = 0; i < CD; ++i) acc += w[i * KK] * row[i];
    }
    P[(c * KK + k) * OPAD + o] = (_Float16)acc;    // o in [100,128) stores 0
}

// ---------- Kernel 2: fused, wave-specialized ----------
// Pre-barrier: all waves stage P->LDS, ballot privacy masks, pack char ids.
// Post-barrier: waves 0-7 = char CNN (LDS pipe), waves 8-15 = word/pos/dist
// (HBM pipe). Both pipes run concurrently on every CU for the whole kernel.
__global__ __launch_bounds__(NTHR, 8) void main_kernel(
        const int* __restrict__ input_word,
        const int* __restrict__ input_char,
        const int* __restrict__ input_pos,
        const float* __restrict__ word_table,
        const float* __restrict__ pos_table,
        const float* __restrict__ conv_b,
        const _Float16* __restrict__ Pg,
        float* __restrict__ out) {
    __shared__ alignas(16) _Float16 Pl[NC * PROW];         // 76800 B
    __shared__ alignas(16) unsigned char s_char[TPB * CL]; // 2048 B packed char ids
    __shared__ unsigned long long s_mask[LS / 64];         // 64 B  (total 78912 B -> 2 blocks/CU)

    const int tid  = threadIdx.x;
    const int tok0 = blockIdx.x * TPB;

    // ---- 1. P staging loads into regs (all waves) ----
    const uint4* src = (const uint4*)Pg;
    const uint4 s0 = src[tid];
    const uint4 s1 = src[tid + NTHR];
    const uint4 s2 = src[tid + 2 * NTHR];
    const uint4 s3 = src[tid + 3 * NTHR];
    uint4 s4 = {};
    const bool h4 = tid < (NV4 - 4 * NTHR);   // tid < 704 (wave-uniform boundary)
    if (h4) s4 = src[tid + 4 * NTHR];

    // ---- 2. privacy-mask ballot (threads 0..511) ----
    if (tid < LS) {
        const int p = input_pos[(tok0 >> 9) * LS + tid];
        const bool pm = (p == 3) | (p == 7) | (p == 11);
        const unsigned long long b = __ballot(pm);
        if ((tid & 63) == 0) s_mask[tid >> 6] = b;
    }

    // ---- 3. char ids packed to bytes (512 dwords) ----
    if (tid < (TPB * CL) / 4) {
        const int4 c4 = ((const int4*)(input_char + tok0 * CL))[tid];
        ((unsigned*)s_char)[tid] =
            (unsigned)c4.x | ((unsigned)c4.y << 8) | ((unsigned)c4.z << 16) | ((unsigned)c4.w << 24);
    }

    // ---- 4. write staged P to LDS, barrier ----
    {
        uint4* dst = (uint4*)Pl;
        dst[tid] = s0;
        dst[tid + NTHR] = s1;
        dst[tid + 2 * NTHR] = s2;
        dst[tid + 3 * NTHR] = s3;
        if (h4) dst[tid + 4 * NTHR] = s4;
    }
    __syncthreads();

    if (tid < 512) {
        // ================== CHAR ROLE: waves 0-7 ==================
        const int wid  = tid >> 6;
        const int lane = tid & 63;
        const int l    = lane & 15;          // filter octet (0..15)
        const char* Pb = (const char*)Pl + l * 16;
        const unsigned* s_cw = (const unsigned*)s_char;

        #pragma unroll 1
        for (int pass = 0; pass < 2; ++pass) {
            const int tb = wid * 8 + pass * 4 + (lane >> 4);   // token in block
            h2 a0[4], a1[4], m[4];
            #pragma unroll
            for (int i = 0; i < 4; ++i) {
                a0[i] = (h2)(_Float16)0;
                a1[i] = (h2)(_Float16)0;
                m[i]  = (h2)(_Float16)(-60000.f);
            }
            #pragma unroll 2
            for (int w = 0; w < CL / 4; ++w) {
                const unsigned wd = s_cw[tb * (CL / 4) + w];   // 4 packed char ids
                #pragma unroll
                for (int b = 0; b < 4; ++b) {
                    const int ca = (int)((wd >> (8 * b)) & 0xFFu) * (PROW * 2);
                    const uint4 r0 = *(const uint4*)(Pb + ca + 0 * (OPAD * 2));
                    const uint4 r1 = *(const uint4*)(Pb + ca + 1 * (OPAD * 2));
                    const uint4 r2 = *(const uint4*)(Pb + ca + 2 * (OPAD * 2));
                    #pragma unroll
                    for (int i = 0; i < 4; ++i) {
                        const unsigned c0 = (i == 0) ? r0.x : (i == 1) ? r0.y : (i == 2) ? r0.z : r0.w;
                        const unsigned c1 = (i == 0) ? r1.x : (i == 1) ? r1.y : (i == 2) ? r1.z : r1.w;
                        const unsigned c2 = (i == 0) ? r2.x : (i == 1) ? r2.y : (i == 2) ? r2.z : r2.w;
                        const h2 p0 = __builtin_bit_cast(h2, c0);
                        const h2 p1 = __builtin_bit_cast(h2, c1);
                        const h2 p2 = __builtin_bit_cast(h2, c2);
                        const h2 y = a0[i] + p2;               // y[t]
                        m[i]  = __builtin_elementwise_max(m[i], y);
                        a0[i] = a1[i] + p1;
                        a1[i] = p0;
                    }
                }
            }
            // tail: y[32] = a0, y[33] = a1; write cols 301..400
            if (l < 13) {
                float mm[8];
                #pragma unroll
                for (int i = 0; i < 4; ++i) {
                    const h2 v = __builtin_elementwise_max(m[i], __builtin_elementwise_max(a0[i], a1[i]));
                    mm[2 * i]     = (float)v.x;
                    mm[2 * i + 1] = (float)v.y;
                }
                const float4 b0 = *(const float4*)(conv_b + 8 * l);
                float* outc = out + (size_t)(tok0 + tb) * OUTD + 301 + 8 * l;
                outc[0] = tanhf(mm[0] + b0.x);
                outc[1] = tanhf(mm[1] + b0.y);
                outc[2] = tanhf(mm[2] + b0.z);
                outc[3] = tanhf(mm[3] + b0.w);
                if (l < 12) {
                    const float4 b1 = *(const float4*)(conv_b + 8 * l + 4);
                    outc[4] = tanhf(mm[4] + b1.x);
                    outc[5] = tanhf(mm[5] + b1.y);
                    outc[6] = tanhf(mm[6] + b1.z);
                    outc[7] = tanhf(mm[7] + b1.w);
                }
            }
        }
    } else {
        // ================== COPY ROLE: waves 8-15 ==================
        const int t2 = tid - 512;

        // word: out[:, 1:301] — float4 gathers, scalar stores
        for (int i = t2; i < TPB * (WD / 4); i += 512) {
            const int t = i / (WD / 4);
            const int j = i - t * (WD / 4);
            const int w = input_word[tok0 + t];
            const float4 v = ((const float4*)word_table)[(size_t)w * (WD / 4) + j];
            float* o = out + (size_t)(tok0 + t) * OUTD + 1 + 4 * j;
            o[0] = v.x; o[1] = v.y; o[2] = v.z; o[3] = v.w;
        }
        // pos: out[:, 401:501]
        for (int i = t2; i < TPB * (PD / 4); i += 512) {
            const int t = i / (PD / 4);
            const int j = i - t * (PD / 4);
            const int p = input_pos[tok0 + t];
            const float4 v = ((const float4*)pos_table)[p * (PD / 4) + j];
            float* o = out + (size_t)(tok0 + t) * OUTD + 401 + 4 * j;
            o[0] = v.x; o[1] = v.y; o[2] = v.z; o[3] = v.w;
        }
        // privacy distance: out[:, 0]
        if (t2 < TPB) {
            const int j = (tok0 & (LS - 1)) + t2;
            const int wj = j >> 6, bj = j & 63;
            int last = -1000;
            {
                unsigned long long x = s_mask[wj] & ((2ull << bj) - 1ull);
                int w = wj;
                while (true) {
                    if (x) { last = w * 64 + 63 - __clzll(x); break; }
                    if (--w < 0) break;
                    x = s_mask[w];
                }
            }
            int nxt = 1000;
            {
                unsigned long long x = s_mask[wj] & (~0ull << bj);
                int w = wj;
                while (true) {
                    if (x) { nxt = w * 64 + (int)__ffsll((long long)x) - 1; break; }
                    if (++w >= LS / 64) break;
                    x = s_mask[w];
                }
            }
            out[(size_t)(tok0 + t2) * OUTD] = (float)min(j - last, nxt - j);
        }
    }
}

extern "C" void kernel_launch(void* const* d_in, const int* in_sizes, int n_in,
                              void* d_out, int out_size, void* d_ws, size_t ws_size,
                              hipStream_t stream) {
    const int*   input_word = (const int*)d_in[0];
    const int*   input_char = (const int*)d_in[1];
    const int*   input_pos  = (const int*)d_in[2];
    const float* word_table = (const float*)d_in[3];
    const float* char_table = (const float*)d_in[4];
    const float* pos_table  = (const float*)d_in[5];
    const float* conv_w     = (const float*)d_in[6];
    const float* conv_b     = (const float*)d_in[7];
    float* out = (float*)d_out;

    _Float16* P = (_Float16*)d_ws;                             // 76800 B

    precompute_P<<<dim3(NC, KK), 128, 0, stream>>>(conv_w, char_table, P);
    main_kernel<<<(BS * LS) / TPB, NTHR, 0, stream>>>(
        input_word, input_char, input_pos, word_table, pos_table, conv_b, P, out);
}